// Round 1
// baseline (453.514 us; speedup 1.0000x reference)
//
#include <hip/hip_runtime.h>
#include <stdint.h>
#include <math.h>

// SFIS: F=16, D=64, N=100000, B=2048, ORDER=3, BETA=1e-4, H=64
#define NB    2048
#define NE    680     // 120 pairs + 560 triples
#define L1N   120
#define L2N   560
#define KEEP2 455     // triples with A<=12 feed the regularizer
#define ROWP  68      // padded LDS row stride (floats) for V0f/Z0f

// JAX >= 0.5 defaults jax_threefry_partitionable=True. If absmax ~0.3 next
// round, flip this to 0 (legacy split-halves counter scheme).
#define THREEFRY_PARTITIONABLE 1

__device__ __forceinline__ uint32_t rotl32(uint32_t v, uint32_t d) {
  return (v << d) | (v >> (32u - d));
}

// JAX threefry2x32 (jax/_src/prng.py), 20 rounds.
__device__ __forceinline__ void tf2x32(uint32_t k0, uint32_t k1,
                                       uint32_t c0, uint32_t c1,
                                       uint32_t &o0, uint32_t &o1) {
  uint32_t ks2 = k0 ^ k1 ^ 0x1BD11BDAu;
  uint32_t x0 = c0 + k0;
  uint32_t x1 = c1 + k1;
#define TF_R(r) { x0 += x1; x1 = rotl32(x1, r); x1 ^= x0; }
  TF_R(13) TF_R(15) TF_R(26) TF_R(6)
  x0 += k1;  x1 += ks2 + 1u;
  TF_R(17) TF_R(29) TF_R(16) TF_R(24)
  x0 += ks2; x1 += k0 + 2u;
  TF_R(13) TF_R(15) TF_R(26) TF_R(6)
  x0 += k0;  x1 += k1 + 3u;
  TF_R(17) TF_R(29) TF_R(16) TF_R(24)
  x0 += k1;  x1 += ks2 + 4u;
  TF_R(13) TF_R(15) TF_R(26) TF_R(6)
  x0 += ks2; x1 += k0 + 5u;
#undef TF_R
  o0 = x0; o1 = x1;
}

__global__ __launch_bounds__(256) void sfis_main(
    const int*   __restrict__ x,
    const float* __restrict__ M,
    const float* __restrict__ w0,
    const float* __restrict__ w_table,
    const float* __restrict__ V_table,
    const float* __restrict__ Z_table,
    const float* __restrict__ W1,
    const float* __restrict__ b1,
    const float* __restrict__ W2,
    const float* __restrict__ b2,
    float* __restrict__ out,
    float* __restrict__ reg_partial) {
  __shared__ __align__(16) float V0s[17 * ROWP];  // row 16 = ones
  __shared__ __align__(16) float Z0s[17 * ROWP];
  __shared__ __align__(16) float Vraw[16][64];
  __shared__ __align__(16) float Zraw[16][64];
  __shared__ __align__(16) float W1s[64 * 64];
  __shared__ float W2s[64];
  __shared__ float b1s[64];
  __shared__ uint32_t descs[NE];
  __shared__ int xs[16];
  __shared__ float red[256];
  __shared__ float wsum_s, w2sum_s;

  const int b   = blockIdx.x;
  const int tid = threadIdx.x;

  // ---- phase A: indices, weights, interaction descriptors ----
  if (tid < 16) xs[tid] = x[b * 16 + tid];
  for (int i = tid; i < 4096; i += 256) W1s[i] = W1[i];
  if (tid < 64) { W2s[tid] = W2[tid]; b1s[tid] = b1[tid]; }
  for (int e = tid; e < NE; e += 256) {
    int fi, fj, fl, lvl;
    if (e < L1N) {                      // pair: V0f[a+1] * V0f[k]
      int a = 0;
      while ((a + 1) * (a + 2) / 2 <= e) ++a;
      int k = e - a * (a + 1) / 2;
      fi = a + 1; fj = k; fl = 16; lvl = 0;   // fl=16 -> ones row
    } else {                            // triple: V0f[A+2] * (V0f[a1+1]*V0f[k1])
      int e2 = e - L1N;
      int A = 0;
      while ((A + 1) * (A + 2) * (A + 3) / 6 <= e2) ++A;
      int k = e2 - A * (A + 1) * (A + 2) / 6;
      int a1 = 0;
      while ((a1 + 1) * (a1 + 2) / 2 <= k) ++a1;
      int k1 = k - a1 * (a1 + 1) / 2;
      fi = A + 2; fj = a1 + 1; fl = k1; lvl = 1;
    }
    descs[e] = (uint32_t)fi | ((uint32_t)fj << 5) | ((uint32_t)fl << 10) |
               ((uint32_t)lvl << 15);
  }
  __syncthreads();

  // ---- phase B: gather V/Z rows, first-order w ----
  for (int idx = tid; idx < 1024; idx += 256) {
    int g = idx >> 6, d = idx & 63;
    long off = (long)xs[g] * 64 + d;
    Vraw[g][d] = V_table[off];
    Zraw[g][d] = Z_table[off];
  }
  if (tid < 16) red[tid] = w_table[xs[tid]];
  __syncthreads();

  // ---- phase C: V0f = M @ V, Z0f = M @ Z ----
  if (tid == 0) {
    float s = 0.f, s2 = 0.f;
    for (int f = 0; f < 16; ++f) { float wv = red[f]; s += wv; s2 += wv * wv; }
    wsum_s = s; w2sum_s = s2;
  }
  for (int idx = tid; idx < 1024; idx += 256) {
    int f = idx >> 6, d = idx & 63;
    float av = 0.f, az = 0.f;
    for (int g = 0; g < 16; ++g) {
      float m = M[f * 16 + g];
      av = fmaf(m, Vraw[g][d], av);
      az = fmaf(m, Zraw[g][d], az);
    }
    V0s[f * ROWP + d] = av;
    Z0s[f * ROWP + d] = az;
  }
  if (tid < 64) { V0s[16 * ROWP + tid] = 1.f; Z0s[16 * ROWP + tid] = 1.f; }
  __syncthreads();

  // ---- phase D: interactions ----
  uint32_t fkA0, fkA1, fkB0, fkB1;   // fold_in(key(42), 0) and (.,1)
  tf2x32(0u, 42u, 0u, 0u, fkA0, fkA1);
  tf2x32(0u, 42u, 0u, 1u, fkB0, fkB1);
  const float b2v = b2[0];

  float yacc = 0.f, v2acc = 0.f;

#define MLP_STEP(ZD, ROWBASE) {                                          \
    const float4* wr_ = (const float4*)&W1s[(ROWBASE) + (jb << 4)];      \
    float4 wa_ = wr_[0], wb_ = wr_[1], wc_ = wr_[2], wd_ = wr_[3];       \
    h[0]  = fmaf(ZD, wa_.x, h[0]);  h[1]  = fmaf(ZD, wa_.y, h[1]);       \
    h[2]  = fmaf(ZD, wa_.z, h[2]);  h[3]  = fmaf(ZD, wa_.w, h[3]);       \
    h[4]  = fmaf(ZD, wb_.x, h[4]);  h[5]  = fmaf(ZD, wb_.y, h[5]);       \
    h[6]  = fmaf(ZD, wb_.z, h[6]);  h[7]  = fmaf(ZD, wb_.w, h[7]);       \
    h[8]  = fmaf(ZD, wc_.x, h[8]);  h[9]  = fmaf(ZD, wc_.y, h[9]);       \
    h[10] = fmaf(ZD, wc_.z, h[10]); h[11] = fmaf(ZD, wc_.w, h[11]);      \
    h[12] = fmaf(ZD, wd_.x, h[12]); h[13] = fmaf(ZD, wd_.y, h[13]);      \
    h[14] = fmaf(ZD, wd_.z, h[14]); h[15] = fmaf(ZD, wd_.w, h[15]); }

  for (int e = tid; e < NE; e += 256) {
    uint32_t dsc = descs[e];
    int fi  = dsc & 31;
    int fj  = (dsc >> 5) & 31;
    int fl  = (dsc >> 10) & 31;
    int lvl = (dsc >> 15) & 1;

    const float4* Vi = (const float4*)&V0s[fi * ROWP];
    const float4* Vj = (const float4*)&V0s[fj * ROWP];
    const float4* Vl = (const float4*)&V0s[fl * ROWP];
    const float4* Zi = (const float4*)&Z0s[fi * ROWP];
    const float4* Zj = (const float4*)&Z0s[fj * ROWP];
    const float4* Zl = (const float4*)&Z0s[fl * ROWP];

    // Wt = sum_d V_sel, vsq = sum_d V_sel^2  (grouping: vi*(vj*vl))
    float wt = 0.f, vsq = 0.f;
#pragma unroll 4
    for (int dq = 0; dq < 16; ++dq) {
      float4 a = Vj[dq], c = Vl[dq], v = Vi[dq];
      float p0 = v.x * (a.x * c.x);
      float p1 = v.y * (a.y * c.y);
      float p2 = v.z * (a.z * c.z);
      float p3 = v.w * (a.w * c.w);
      wt  += p0 + p1 + p2 + p3;
      vsq += p0 * p0 + p1 * p1 + p2 * p2 + p3 * p3;
    }

    // MLP: z1 = Z_sel @ W1 + b1; t2 = relu(z1) @ W2 + b2
    float t2 = 0.f;
    for (int jb = 0; jb < 4; ++jb) {
      float h[16];
#pragma unroll
      for (int jj = 0; jj < 16; ++jj) h[jj] = b1s[(jb << 4) + jj];
      for (int dq = 0; dq < 16; ++dq) {
        float4 a = Zj[dq], c = Zl[dq], zz = Zi[dq];
        float z0 = zz.x * (a.x * c.x);
        float z1 = zz.y * (a.y * c.y);
        float z2 = zz.z * (a.z * c.z);
        float z3 = zz.w * (a.w * c.w);
        const int rb = dq << 8;  // dq*4 rows * 64
        MLP_STEP(z0, rb)
        MLP_STEP(z1, rb + 64)
        MLP_STEP(z2, rb + 128)
        MLP_STEP(z3, rb + 192)
      }
#pragma unroll
      for (int jj = 0; jj < 16; ++jj)
        t2 += fmaxf(h[jj], 0.f) * W2s[(jb << 4) + jj];
    }
    t2 += b2v;

    // eps: JAX uniform from threefry
    uint32_t Lsz  = lvl ? (uint32_t)L2N : (uint32_t)L1N;
    uint32_t lidx = lvl ? (uint32_t)(e - L1N) : (uint32_t)e;
    uint32_t kk0  = lvl ? fkB0 : fkA0;
    uint32_t kk1  = lvl ? fkB1 : fkA1;
    uint32_t gi   = (uint32_t)b * Lsz + lidx;
    uint32_t o0, o1, bits;
#if THREEFRY_PARTITIONABLE
    tf2x32(kk0, kk1, 0u, gi, o0, o1);
    bits = o0 ^ o1;
#else
    {
      uint32_t half = Lsz * (NB / 2);
      if (gi < half) { tf2x32(kk0, kk1, gi, gi + half, o0, o1); bits = o0; }
      else           { tf2x32(kk0, kk1, gi - half, gi, o0, o1); bits = o1; }
    }
#endif
    float eps = __uint_as_float((bits >> 9) | 0x3f800000u) - 1.0f;

    double ex = exp(-(double)t2);
    float pro = (float)(1.0 / (1.0 + ex));
    if (pro >= eps) yacc += wt;
    if (lvl && (uint32_t)(e - L1N) < (uint32_t)KEEP2) v2acc += vsq;
  }
#undef MLP_STEP

  // ---- phase E: reductions ----
  red[tid] = yacc;
  __syncthreads();
  for (int s = 128; s > 0; s >>= 1) {
    if (tid < s) red[tid] += red[tid + s];
    __syncthreads();
  }
  if (tid == 0) out[b] = w0[0] + wsum_s + red[0];
  __syncthreads();

  red[tid] = v2acc;
  __syncthreads();
  for (int s = 128; s > 0; s >>= 1) {
    if (tid < s) red[tid] += red[tid + s];
    __syncthreads();
  }
  if (tid == 0) reg_partial[b] = w2sum_s + red[0];
}

__global__ __launch_bounds__(256) void sfis_reduce(
    const float* __restrict__ reg_partial, float* __restrict__ out) {
  __shared__ float red[256];
  int tid = threadIdx.x;
  float s = 0.f;
  for (int i = tid; i < NB; i += 256) s += reg_partial[i];
  red[tid] = s;
  __syncthreads();
  for (int st = 128; st > 0; st >>= 1) {
    if (tid < st) red[tid] += red[tid + st];
    __syncthreads();
  }
  if (tid == 0) out[NB] = 1.0e-4f * red[0];  // BETA
}

extern "C" void kernel_launch(void* const* d_in, const int* in_sizes, int n_in,
                              void* d_out, int out_size, void* d_ws, size_t ws_size,
                              hipStream_t stream) {
  (void)in_sizes; (void)n_in; (void)out_size; (void)ws_size;
  const int*   x       = (const int*)  d_in[0];
  const float* M       = (const float*)d_in[1];
  const float* w0      = (const float*)d_in[2];
  const float* w_table = (const float*)d_in[3];
  const float* V_table = (const float*)d_in[4];
  const float* Z_table = (const float*)d_in[5];
  const float* W1      = (const float*)d_in[6];
  const float* b1      = (const float*)d_in[7];
  const float* W2      = (const float*)d_in[8];
  const float* b2      = (const float*)d_in[9];
  float* out  = (float*)d_out;
  float* regp = (float*)d_ws;   // 2048 partials

  hipLaunchKernelGGL(sfis_main, dim3(NB), dim3(256), 0, stream,
                     x, M, w0, w_table, V_table, Z_table, W1, b1, W2, b2,
                     out, regp);
  hipLaunchKernelGGL(sfis_reduce, dim3(1), dim3(256), 0, stream, regp, out);
}